// Round 11
// baseline (52.892 us; speedup 1.0000x reference)
//
#include <hip/hip_runtime.h>
#include <math.h>

#define B_   8
#define C_   128
#define H_   128
#define W_   128
#define TS   32                   // 32x32 output tile
#define PAD  3
#define HS   (TS + 2*PAD)         // 38
#define NPOS (HS*HS)              // 1444 halo positions
#define NC   4                    // channels packed per LDS position (f16x4 = 8 B)
#define CPB  16                   // channels per block
#define NGRP (CPB/NC)             // 4
#define NCHUNK (C_/CPB)           // 8
#define NSLOT 6                   // ceil(1444/256)
#define REM  (NPOS - 5*256)       // 164

typedef __fp16 h2v __attribute__((ext_vector_type(2)));

struct KTab { float sk[4][25]; };  // 25 symmetry-unique taps: K[t]==K[48-t]

__device__ __forceinline__ int refl(int i, int n) {
    if (i < 0) i = -i;
    if (i >= n) i = 2*n - 2 - i;
    return i;
}

__device__ __forceinline__ uint2 pack4(const float4& v) {
    unsigned lo = __builtin_bit_cast(unsigned, __builtin_amdgcn_cvt_pkrtz(v.x, v.y));
    unsigned hi = __builtin_bit_cast(unsigned, __builtin_amdgcn_cvt_pkrtz(v.z, v.w));
    return make_uint2(lo, hi);
}

// dword k (0..15) of a 4 x uint4 register block; k is always a literal.
__device__ __forceinline__ unsigned dw(const uint4 L[4], int k) {
    const uint4 v = L[k >> 2];
    switch (k & 3) {
        case 0: return v.x;
        case 1: return v.y;
        case 2: return v.z;
        default: return v.w;
    }
}

__global__ __launch_bounds__(256, 2) void ddconv_kernel(
    const float* __restrict__ x,      // [B,C,H,W]
    const float* __restrict__ angle,  // [B,H,W]
    const float* __restrict__ w1,     // [8,2]
    const float* __restrict__ b1,     // [8]
    const float* __restrict__ w2,     // [4,8]
    const float* __restrict__ b2,     // [4]
    float* __restrict__ out,          // [B,C,H,W]
    KTab kt)
{
    // position-major halo tile, 4 channels as f16x4 (8 B) per position
    __shared__ __align__(16) uint2 sb[2][NPOS];   // 2 * 11552 = 23104 B

    const int tid = threadIdx.x;
    const int hx  = tid & 15;          // horiz pair: local cols 2hx, 2hx+1
    const int ty  = tid >> 4;          // vert pair: local rows 2ty, 2ty+1
    const int bx  = blockIdx.x;        // 16 tiles (4x4)
    const int TX0 = (bx & 3) * TS;
    const int TY0 = (bx >> 2) * TS;
    const int b   = blockIdx.y;
    const int c0  = blockIdx.z * CPB;
    const int ox  = TX0 + 2*hx;
    const int oy  = TY0 + 2*ty;
    const size_t HW = (size_t)H_ * W_;

    // ---- staging geometry ----
    int off[NSLOT];
#pragma unroll
    for (int s = 0; s < NSLOT; ++s) {
        int p = tid + s*256;
        if (p >= NPOS) p = NPOS - 1;
        int gy = refl(TY0 + p/HS - PAD, H_);
        int gx = refl(TX0 + p%HS - PAD, W_);
        off[s] = gy*W_ + gx;
    }
    const bool hasR = (tid < REM);

    // ---- prologue: issue group-0 stage loads ----
    float4 pv[NSLOT];
    {
        const float* xb = x + ((size_t)(b*C_ + c0))*HW;
#pragma unroll
        for (int s = 0; s < NSLOT; ++s) {
            if (s == NSLOT-1 && !hasR) break;
            pv[s].x = xb[0*HW + off[s]]; pv[s].y = xb[1*HW + off[s]];
            pv[s].z = xb[2*HW + off[s]]; pv[s].w = xb[3*HW + off[s]];
        }
    }

    // ---- per-pixel gating for the 2x2 footprint (hides load latency) ----
    float wt[2][2][4];                 // [vert v][horiz h][dir]
#pragma unroll
    for (int v = 0; v < 2; ++v) {
        float2 a2 = *reinterpret_cast<const float2*>(
            &angle[((size_t)b*H_ + (oy+v))*W_ + ox]);
#pragma unroll
        for (int h = 0; h < 2; ++h) {
            float a = (h == 0) ? a2.x : a2.y;
            float s = __sinf(2.f*a), c = __cosf(2.f*a);
            float hv[8];
#pragma unroll
            for (int j = 0; j < 8; ++j) {
                float q = fmaf(s, w1[2*j], fmaf(c, w1[2*j+1], b1[j]));
                hv[j] = q > 0.f ? q : 0.f;
            }
            float lg[4];
#pragma unroll
            for (int d = 0; d < 4; ++d) {
                float q = b2[d];
#pragma unroll
                for (int j = 0; j < 8; ++j) q = fmaf(hv[j], w2[d*8+j], q);
                lg[d] = q;
            }
            float m  = fmaxf(fmaxf(lg[0], lg[1]), fmaxf(lg[2], lg[3]));
            float e0 = __expf(lg[0]-m), e1 = __expf(lg[1]-m);
            float e2 = __expf(lg[2]-m), e3 = __expf(lg[3]-m);
            float inv = 1.f / (e0+e1+e2+e3);
            wt[v][h][0] = e0*inv; wt[v][h][1] = e1*inv;
            wt[v][h][2] = e2*inv; wt[v][h][3] = e3*inv;
        }
    }

    // ---- blend + pack: 4 px x 25 taps as f16 pairs (52 dwords) ----
    h2v kbh[2][2][13];
#pragma unroll
    for (int pr = 0; pr < 13; ++pr) {
        const int u0 = 2*pr, u1 = 2*pr + 1;   // u1==25 -> pad
        const float s00 = kt.sk[0][u0], s10 = kt.sk[1][u0],
                    s20 = kt.sk[2][u0], s30 = kt.sk[3][u0];
        float s01 = 0.f, s11 = 0.f, s21 = 0.f, s31 = 0.f;
        if (u1 < 25) { s01 = kt.sk[0][u1]; s11 = kt.sk[1][u1];
                       s21 = kt.sk[2][u1]; s31 = kt.sk[3][u1]; }
#pragma unroll
        for (int v = 0; v < 2; ++v)
#pragma unroll
            for (int h = 0; h < 2; ++h) {
                float k0 = wt[v][h][0]*s00 + wt[v][h][1]*s10
                         + wt[v][h][2]*s20 + wt[v][h][3]*s30;
                float k1 = wt[v][h][0]*s01 + wt[v][h][1]*s11
                         + wt[v][h][2]*s21 + wt[v][h][3]*s31;
                kbh[v][h][pr] = __builtin_amdgcn_cvt_pkrtz(k0, k1);
            }
    }

    // ---- pack + write group-0 tile ----
#pragma unroll
    for (int s = 0; s < NSLOT; ++s) {
        if (s == NSLOT-1 && !hasR) break;
        sb[0][tid + s*256] = pack4(pv[s]);
    }

    for (int g = 0; g < NGRP; ++g) {
        __syncthreads();   // sb[g&1] ready; prior readers of sb[(g+1)&1] done

        // issue next group's stage loads EARLY
        const bool doStage = (g + 1 < NGRP);
        if (doStage) {
            const float* xb = x + ((size_t)(b*C_ + c0 + (g+1)*NC))*HW;
#pragma unroll
            for (int s = 0; s < NSLOT; ++s) {
                if (s == NSLOT-1 && !hasR) break;
                pv[s].x = xb[0*HW + off[s]]; pv[s].y = xb[1*HW + off[s]];
                pv[s].z = xb[2*HW + off[s]]; pv[s].w = xb[3*HW + off[s]];
            }
        }

        // ---- conv: 2x2 px x 4 ch; 4 x ds_read_b128 per row (8 positions) ----
        const uint4* lds4 = reinterpret_cast<const uint4*>(&sb[g & 1][0]);
        float acc[2][2][4];
#pragma unroll
        for (int v = 0; v < 2; ++v)
#pragma unroll
            for (int h = 0; h < 2; ++h)
#pragma unroll
                for (int ch = 0; ch < 4; ++ch) acc[v][h][ch] = 0.f;

#pragma unroll
        for (int r = 0; r < 8; ++r) {
            const int base = (2*ty + r)*19 + hx;   // uint4 index (row stride 38 pos = 19 uint4)
            uint4 L[4];
            L[0] = lds4[base]; L[1] = lds4[base+1];
            L[2] = lds4[base+2]; L[3] = lds4[base+3];
#pragma unroll
            for (int v = 0; v < 2; ++v) {
                const int i = r - v;
                if (i < 0 || i > 6) continue;
#pragma unroll
                for (int j = 0; j < 7; ++j) {
                    const int t = i*7 + j;
                    const int u = (t <= 24) ? t : 48 - t;   // central symmetry
#pragma unroll
                    for (int h = 0; h < 2; ++h) {
                        const int q = j + h;                // 0..7
                        h2v c01 = __builtin_bit_cast(h2v, dw(L, 2*q));
                        h2v c23 = __builtin_bit_cast(h2v, dw(L, 2*q + 1));
                        h2v kw  = kbh[v][h][u >> 1];
                        float kf = (u & 1) ? (float)kw.y : (float)kw.x;
                        acc[v][h][0] = fmaf((float)c01.x, kf, acc[v][h][0]);
                        acc[v][h][1] = fmaf((float)c01.y, kf, acc[v][h][1]);
                        acc[v][h][2] = fmaf((float)c23.x, kf, acc[v][h][2]);
                        acc[v][h][3] = fmaf((float)c23.y, kf, acc[v][h][3]);
                    }
                }
            }
        }

        // ---- store 2x2 x 4 ch as float2 (coalesced, full lines per wave) ----
#pragma unroll
        for (int ch = 0; ch < 4; ++ch) {
            float* ob = out + ((size_t)(b*C_ + c0 + g*NC + ch))*HW
                            + (size_t)oy*W_ + ox;
#pragma unroll
            for (int v = 0; v < 2; ++v) {
                float2 st = {acc[v][0][ch], acc[v][1][ch]};
                *reinterpret_cast<float2*>(&ob[v*W_]) = st;
            }
        }

        // write-late: pack + store next group's tile into the other buffer
        if (doStage) {
            uint2* nb = sb[(g+1) & 1];
#pragma unroll
            for (int s = 0; s < NSLOT; ++s) {
                if (s == NSLOT-1 && !hasR) break;
                nb[tid + s*256] = pack4(pv[s]);
            }
        }
    }
}

static KTab make_ktab() {
    KTab t;
    const double sig1 = 2.5, sig2 = 1.0;
    const double angles[4] = {0.0, M_PI/4.0, M_PI/2.0, 3.0*M_PI/4.0};
    for (int d = 0; d < 4; ++d) {
        double th = angles[d], cs = cos(th), sn = sin(th);
        double sum = 0.0, k[7][7];
        for (int i = 0; i < 7; ++i) for (int j = 0; j < 7; ++j) {
            double xx = i - 3, yy = j - 3;
            double xr = xx*cs + yy*sn, yr = -xx*sn + yy*cs;
            k[i][j] = exp(-(xr*xr/(2.0*sig1*sig1) + yr*yr/(2.0*sig2*sig2)));
            sum += k[i][j];
        }
        for (int u = 0; u < 25; ++u)
            t.sk[d][u] = (float)(k[u/7][u%7]/sum);
    }
    return t;
}

extern "C" void kernel_launch(void* const* d_in, const int* in_sizes, int n_in,
                              void* d_out, int out_size, void* d_ws, size_t ws_size,
                              hipStream_t stream) {
    const float* x     = (const float*)d_in[0];
    const float* angle = (const float*)d_in[1];
    const float* w1    = (const float*)d_in[2];
    const float* b1    = (const float*)d_in[3];
    const float* w2    = (const float*)d_in[4];
    const float* b2    = (const float*)d_in[5];
    float* out = (float*)d_out;

    static const KTab kt = make_ktab();   // deterministic; host-side, no HIP calls

    dim3 grid((W_/TS)*(H_/TS), B_, NCHUNK);   // 16 x 8 x 8 = 1024 blocks
    dim3 block(256);
    ddconv_kernel<<<grid, block, 0, stream>>>(x, angle, w1, b1, w2, b2, out, kt);
}